// Round 5
// baseline (1184.038 us; speedup 1.0000x reference)
//
#include <hip/hip_runtime.h>
#include <math.h>

#define BB 512   // batch
#define TT 256   // time steps
#define EE 128   // hidden
#define GG 512   // 4*E gates
#define XROW 257 // T+1

// sigmoid and tanh via one shared exp path: tanh(x) = 2*sigmoid(2x) - 1
__device__ __forceinline__ float sig_(float v) {
    return 1.0f / (1.0f + __expf(-v));
}
__device__ __forceinline__ float tanh2_(float v) {
    return fmaf(2.0f, sig_(2.0f * v), -1.0f);
}

// Thread (rg = t&127, cg = t>>7) owns rows 4rg..4rg+3 x cols 16cg..16cg+15.
// 64 weights live in 64 NAMED SCALAR floats (scalar "+v" asm keep-alive is
// supported; float4 tied operands are not -- round-4 compile failure).
#define DECL_ROW(R) float w##R##_0,w##R##_1,w##R##_2,w##R##_3,w##R##_4,w##R##_5, \
  w##R##_6,w##R##_7,w##R##_8,w##R##_9,w##R##_10,w##R##_11,w##R##_12,w##R##_13, \
  w##R##_14,w##R##_15
#define DECLW DECL_ROW(0); DECL_ROW(1); DECL_ROW(2); DECL_ROW(3)

#define LOAD_ROW(R, P) do { const float4* _q = (const float4*)(P); \
  float4 _a=_q[0], _b=_q[1], _c=_q[2], _d=_q[3]; \
  w##R##_0=_a.x;  w##R##_1=_a.y;  w##R##_2=_a.z;  w##R##_3=_a.w; \
  w##R##_4=_b.x;  w##R##_5=_b.y;  w##R##_6=_b.z;  w##R##_7=_b.w; \
  w##R##_8=_c.x;  w##R##_9=_c.y;  w##R##_10=_c.z; w##R##_11=_c.w; \
  w##R##_12=_d.x; w##R##_13=_d.y; w##R##_14=_d.z; w##R##_15=_d.w; } while(0)
#define LOADW(P) do { const float* _pp = (P); \
  LOAD_ROW(0, _pp); LOAD_ROW(1, _pp + EE); \
  LOAD_ROW(2, _pp + 2*EE); LOAD_ROW(3, _pp + 3*EE); } while(0)

#define KEEP_ROW(R) asm volatile("" : \
  "+v"(w##R##_0),"+v"(w##R##_1),"+v"(w##R##_2),"+v"(w##R##_3), \
  "+v"(w##R##_4),"+v"(w##R##_5),"+v"(w##R##_6),"+v"(w##R##_7), \
  "+v"(w##R##_8),"+v"(w##R##_9),"+v"(w##R##_10),"+v"(w##R##_11), \
  "+v"(w##R##_12),"+v"(w##R##_13),"+v"(w##R##_14),"+v"(w##R##_15))
#define KEEPW do { KEEP_ROW(0); KEEP_ROW(1); KEEP_ROW(2); KEEP_ROW(3); } while(0)

#define FMA_ROW(R, A) do { \
  A=fmaf(w##R##_0 , x0.x, A); A=fmaf(w##R##_1 , x0.y, A); \
  A=fmaf(w##R##_2 , x0.z, A); A=fmaf(w##R##_3 , x0.w, A); \
  A=fmaf(w##R##_4 , x1.x, A); A=fmaf(w##R##_5 , x1.y, A); \
  A=fmaf(w##R##_6 , x1.z, A); A=fmaf(w##R##_7 , x1.w, A); \
  A=fmaf(w##R##_8 , x2.x, A); A=fmaf(w##R##_9 , x2.y, A); \
  A=fmaf(w##R##_10, x2.z, A); A=fmaf(w##R##_11, x2.w, A); \
  A=fmaf(w##R##_12, x3.x, A); A=fmaf(w##R##_13, x3.y, A); \
  A=fmaf(w##R##_14, x3.z, A); A=fmaf(w##R##_15, x3.w, A); } while(0)

// dot phase: 4 broadcast ds_read_b128 (h slice reused across 4 rows) + 64 FMA
#define DOT_PHASE() do { \
  const float4* _hp = (const float4*)(h_lds + 16*cg); \
  float4 x0=_hp[0], x1=_hp[1], x2=_hp[2], x3=_hp[3]; \
  float a0=0.f, a1=0.f, a2=0.f, a3=0.f; \
  FMA_ROW(0,a0); FMA_ROW(1,a1); FMA_ROW(2,a2); FMA_ROW(3,a3); \
  *(float4*)&part[cg*GG + rg*4] = make_float4(a0,a1,a2,a3); \
} while(0)

// psum + nonlinearity: thread q (<128) produces rows 4q..4q+3.
// Reads are b128, lanes stride 16B -> conflict-free.
__device__ __forceinline__ void psum_nl(const float* part, float* nlg, int q,
                                        float u, float4 cwih4, float4 cb4) {
    float4 s4 = *(const float4*)&part[4 * q];
    #pragma unroll
    for (int c = 1; c < 8; ++c) {
        float4 p4 = *(const float4*)&part[c * GG + 4 * q];
        s4.x += p4.x; s4.y += p4.y; s4.z += p4.z; s4.w += p4.w;
    }
    // rows 4q..4q+3 are one gate type: q in [64,96) -> tanh(g); else sigmoid
    const bool istanh = (q >= 64) && (q < 96);
    const float sc = istanh ? 2.0f : 1.0f;
    const float cc = istanh ? -1.0f : 0.0f;
    float4 n4;
    n4.x = fmaf(sc, sig_(sc * (s4.x + fmaf(u, cwih4.x, cb4.x))), cc);
    n4.y = fmaf(sc, sig_(sc * (s4.y + fmaf(u, cwih4.y, cb4.y))), cc);
    n4.z = fmaf(sc, sig_(sc * (s4.z + fmaf(u, cwih4.z, cb4.z))), cc);
    n4.w = fmaf(sc, sig_(sc * (s4.w + fmaf(u, cwih4.w, cb4.w))), cc);
    *(float4*)&nlg[4 * q] = n4;
}

__global__ __launch_bounds__(1024) __attribute__((amdgpu_waves_per_eu(4, 4)))
void fused_kernel(const float* __restrict__ x,
                  const float* __restrict__ enc_wih,
                  const float* __restrict__ enc_whh,
                  const float* __restrict__ enc_bias,
                  const float* __restrict__ dec_wih,
                  const float* __restrict__ dec_whh,
                  const float* __restrict__ dec_bias,
                  const float* __restrict__ lin_w,
                  const float* __restrict__ lin_b,
                  float* __restrict__ out)
{
    const int t  = threadIdx.x;
    const int rg = t & 127;
    const int cg = t >> 7;
    const int b  = blockIdx.x;

    __shared__ __align__(16) float h_lds[EE];
    __shared__ __align__(16) float part[8 * GG];   // [cg][row] partials, 16 KB
    __shared__ __align__(16) float nlg[GG];        // per-row nonlinearity out
    __shared__ __align__(16) float out_lds[TT];
    __shared__ float xbuf[2];
    __shared__ float osum[2];
    // Occupancy forcing: ~82 KB static LDS -> 1 block (16 waves = 4 waves/EU)
    // per CU -> register allocator budget = 128 VGPRs -> weights stay resident.
    __shared__ float force_occ[15600];

    const int id = (int)x[b * XROW + TT];
    if (id < 0) {  // never true (id in [0,16)) -- keeps force_occ allocated
        force_occ[t] = (float)t;
        if (force_occ[t ^ 1] > 1.0e30f) out_lds[0] = 1.0f;
    }

    DECLW;
    float c_reg = 0.0f;

    float4 cwih4 = make_float4(0.f,0.f,0.f,0.f);
    float4 cb4   = make_float4(0.f,0.f,0.f,0.f);
    const float lb_v = lin_b[id];
    float wl = 0.0f;
    if (t < EE) wl = lin_w[id * EE + t];

    // ---------------- encoder ----------------
    LOADW(enc_whh + (4 * rg) * EE + 16 * cg);
    if (t < EE) {
        cwih4 = *(const float4*)(enc_wih + 4 * t);
        cb4   = *(const float4*)(enc_bias + 4 * t);
        h_lds[t] = 0.0f;
    }
    if (t == 512) xbuf[0] = x[b * XROW + 0];
    __syncthreads();

    for (int s = 0; s < TT; ++s) {
        KEEPW;
        DOT_PHASE();
        __syncthreads();
        if (t < EE) psum_nl(part, nlg, t, xbuf[s & 1], cwih4, cb4);
        if (t == 512 && s + 1 < TT) xbuf[(s + 1) & 1] = x[b * XROW + s + 1];
        __syncthreads();
        if (t < EE) {
            float i_ = nlg[t], f_ = nlg[EE + t], g_ = nlg[2*EE + t], o_ = nlg[3*EE + t];
            c_reg = fmaf(f_, c_reg, i_ * g_);
            h_lds[t] = o_ * tanh2_(c_reg);
        }
        __syncthreads();
    }

    // ---------------- u0 = h_enc . lin_w + lin_b ----------------
    if (t < EE) {
        float p = h_lds[t] * wl;
        #pragma unroll
        for (int off = 32; off >= 1; off >>= 1) p += __shfl_xor(p, off);
        if ((t & 63) == 0) osum[t >> 6] = p;
    }
    __syncthreads();
    if (t == 512) xbuf[0] = osum[0] + osum[1] + lb_v;   // u0

    // ---------------- decoder weights ----------------
    LOADW(dec_whh + id * GG * EE + (4 * rg) * EE + 16 * cg);
    if (t < EE) {
        cwih4 = *(const float4*)(dec_wih + id * GG + 4 * t);
        cb4   = *(const float4*)(dec_bias + id * GG + 4 * t);
    }
    __syncthreads();

    // ---------------- decoder ----------------
    for (int s = 0; s < TT; ++s) {
        KEEPW;
        DOT_PHASE();
        __syncthreads();
        if (t < EE) psum_nl(part, nlg, t, xbuf[s & 1], cwih4, cb4);
        // u_{s+1} = rev[s] = x[b][255-s]
        if (t == 512 && s + 1 < TT) xbuf[(s + 1) & 1] = x[b * XROW + (TT - 1 - s)];
        // previous step's output (osum from step s-1, stable this phase)
        if (t == 513 && s > 0) out_lds[TT - s] = osum[0] + osum[1] + lb_v;
        __syncthreads();
        if (t < EE) {
            float i_ = nlg[t], f_ = nlg[EE + t], g_ = nlg[2*EE + t], o_ = nlg[3*EE + t];
            c_reg = fmaf(f_, c_reg, i_ * g_);
            float h_new = o_ * tanh2_(c_reg);
            h_lds[t] = h_new;
            float p = h_new * wl;
            #pragma unroll
            for (int off = 32; off >= 1; off >>= 1) p += __shfl_xor(p, off);
            if ((t & 63) == 0) osum[t >> 6] = p;
        }
        __syncthreads();
    }
    if (t == 512) out_lds[0] = osum[0] + osum[1] + lb_v;  // step 255 -> pos 0
    __syncthreads();

    if (t < 64) *(float4*)(out + b * TT + 4 * t) = ((const float4*)out_lds)[t];
}

extern "C" void kernel_launch(void* const* d_in, const int* in_sizes, int n_in,
                              void* d_out, int out_size, void* d_ws, size_t ws_size,
                              hipStream_t stream) {
    const float* x       = (const float*)d_in[0];
    const float* enc_wih = (const float*)d_in[1];
    const float* enc_whh = (const float*)d_in[2];
    const float* enc_b   = (const float*)d_in[3];
    const float* dec_wih = (const float*)d_in[4];
    const float* dec_whh = (const float*)d_in[5];
    const float* dec_b   = (const float*)d_in[6];
    const float* lin_w   = (const float*)d_in[7];
    const float* lin_b   = (const float*)d_in[8];
    float* out = (float*)d_out;

    hipLaunchKernelGGL(fused_kernel, dim3(BB), dim3(1024), 0, stream,
                       x, enc_wih, enc_whh, enc_b,
                       dec_wih, dec_whh, dec_b, lin_w, lin_b, out);
}